// Round 12
// baseline (659.606 us; speedup 1.0000x reference)
//
#include <hip/hip_runtime.h>
#include <cstdint>
#include <cstddef>

typedef unsigned short u16;
typedef __attribute__((ext_vector_type(8))) short short8;
typedef __attribute__((ext_vector_type(4))) float floatx4;

typedef const __attribute__((address_space(1))) void g_void;
typedef __attribute__((address_space(3))) void l_void;

__device__ __forceinline__ float b2f(u16 u) {
    union { unsigned int i; float f; } v; v.i = ((unsigned int)u) << 16; return v.f;
}
__device__ __forceinline__ u16 f2b(float f) {
    union { float f; unsigned int i; } v; v.f = f;
    unsigned int x = v.i;
    return (u16)((x + 0x7fffu + ((x >> 16) & 1u)) >> 16);
}
__device__ __forceinline__ float gelu_exact(float x) {
    return 0.5f * x * (1.0f + erff(x * 0.70710678118654752440f));
}

// ------------------------------------------------------------ dtype sniff
__global__ void sniff_kernel(const u16* __restrict__ x, int* __restrict__ flag) {
    int lane = threadIdx.x;
    int sane = 0;
    for (int i = lane * 2; i < 4096; i += 128) {
        int e = (x[i] >> 7) & 0xff;
        if (e >= 100 && e <= 140) sane++;
    }
#pragma unroll
    for (int off = 32; off; off >>= 1) sane += __shfl_xor(sane, off, 64);
    if (lane == 0) *flag = (sane * 2 >= 2048) ? 0 : 1;
}

// ------------------------------------------------------------ any -> bf16 canonical (ctx)
__global__ __launch_bounds__(256) void cvt_bf_kernel(const void* __restrict__ in,
                                                     u16* __restrict__ out, int n4,
                                                     const int* __restrict__ flag) {
    int i = blockIdx.x * 256 + threadIdx.x;
    if (i >= n4) return;
    bool isf = (*flag != 0);
    uint2 pk;
    if (isf) {
        float4 v = ((const float4*)in)[i];
        pk.x = (unsigned)f2b(v.x) | ((unsigned)f2b(v.y) << 16);
        pk.y = (unsigned)f2b(v.z) | ((unsigned)f2b(v.w) << 16);
    } else {
        pk = ((const uint2*)in)[i];
    }
    ((uint2*)out)[i] = pk;
}

// ------------------------------------------------------------ batched transpose+cast: 12 weights in one launch
// 64x64 tiles, 256 threads, 16 elem/thread, fully vectorized (r6: removed the
// scalar-2B version that ran at 21% HBM). LDS row stride 66 u16 = 33 dwords.
struct TEnt { const void* src; u16* dst; int R, C, tiles_x, tiles; };
struct TPack { TEnt e[12]; };

__global__ __launch_bounds__(256) void transpose_batch_kernel(TPack p, const int* __restrict__ flag) {
    TEnt e = p.e[blockIdx.y];
    if ((int)blockIdx.x >= e.tiles) return;
    __shared__ u16 t[64 * 66];
    const bool isf = (*flag != 0);
    const int tid = threadIdx.x;
    const int c0 = (blockIdx.x % e.tiles_x) * 64;
    const int r0 = (blockIdx.x / e.tiles_x) * 64;
    {
        const int row = tid >> 2, cs = tid & 3;          // row 0..63, 16-col seg 0..3
        u16 vv[16];
        if (isf) {
            const float* s = (const float*)e.src + (size_t)(r0 + row) * e.C + c0 + cs * 16;
#pragma unroll
            for (int q = 0; q < 4; q++) {
                float4 f = ((const float4*)s)[q];
                vv[q * 4 + 0] = f2b(f.x); vv[q * 4 + 1] = f2b(f.y);
                vv[q * 4 + 2] = f2b(f.z); vv[q * 4 + 3] = f2b(f.w);
            }
        } else {
            const u16* s = (const u16*)e.src + (size_t)(r0 + row) * e.C + c0 + cs * 16;
            uint4 a = ((const uint4*)s)[0];
            uint4 b = ((const uint4*)s)[1];
            const u16* ap = (const u16*)&a;
            const u16* bp = (const u16*)&b;
#pragma unroll
            for (int q = 0; q < 8; q++) { vv[q] = ap[q]; vv[8 + q] = bp[q]; }
        }
        u16* dl = t + row * 66 + cs * 16;                // byte addr row*132+cs*32: 4B-aligned
#pragma unroll
        for (int q = 0; q < 8; q++)
            ((unsigned*)dl)[q] = (unsigned)vv[2 * q] | ((unsigned)vv[2 * q + 1] << 16);
    }
    __syncthreads();
    {
        const int cc2 = tid >> 3, rs = tid & 7;          // dst col pair 0..31, 8-row seg 0..7
        u16 lo[8], hi[8];
#pragma unroll
        for (int j = 0; j < 8; j++) {
            unsigned w = *(const unsigned*)(t + (size_t)(rs * 8 + j) * 66 + cc2 * 2);
            lo[j] = (u16)w; hi[j] = (u16)(w >> 16);
        }
        uint4 pl, ph;
        pl.x = (unsigned)lo[0] | ((unsigned)lo[1] << 16); pl.y = (unsigned)lo[2] | ((unsigned)lo[3] << 16);
        pl.z = (unsigned)lo[4] | ((unsigned)lo[5] << 16); pl.w = (unsigned)lo[6] | ((unsigned)lo[7] << 16);
        ph.x = (unsigned)hi[0] | ((unsigned)hi[1] << 16); ph.y = (unsigned)hi[2] | ((unsigned)hi[3] << 16);
        ph.z = (unsigned)hi[4] | ((unsigned)hi[5] << 16); ph.w = (unsigned)hi[6] | ((unsigned)hi[7] << 16);
        u16* d0 = e.dst + (size_t)(c0 + cc2 * 2) * e.R + r0 + rs * 8;
        *(uint4*)d0 = pl;
        *(uint4*)(d0 + e.R) = ph;
    }
}

// ------------------------------------------------------------ LayerNorm, row=1024
// raw=0: x is fp32[rows][1024]. raw=1: x is the network input (dtype per flag);
// additionally writes the fp32 copy to xout (residual stream init).
__global__ __launch_bounds__(256) void ln_kernel(const void* __restrict__ x,
                                                 float* __restrict__ xout,
                                                 const void* __restrict__ g,
                                                 const void* __restrict__ bb,
                                                 u16* __restrict__ out,
                                                 const int* __restrict__ flag,
                                                 int raw) {
    const int row = blockIdx.x;
    const int tid = threadIdx.x;
    const int lane = tid & 63, wave = tid >> 6;
    bool isf = (*flag != 0);
    size_t base = (size_t)row * 1024 + tid * 4;
    float4 xv;
    if (raw && !isf) {
        uint2 w = ((const uint2*)x)[base >> 2];
        xv.x = b2f((u16)(w.x & 0xffff)); xv.y = b2f((u16)(w.x >> 16));
        xv.z = b2f((u16)(w.y & 0xffff)); xv.w = b2f((u16)(w.y >> 16));
    } else {
        xv = ((const float4*)x)[base >> 2];
    }
    if (raw) ((float4*)xout)[base >> 2] = xv;
    float s  = xv.x + xv.y + xv.z + xv.w;
    float s2 = xv.x * xv.x + xv.y * xv.y + xv.z * xv.z + xv.w * xv.w;
#pragma unroll
    for (int off = 32; off; off >>= 1) {
        s  += __shfl_xor(s, off, 64);
        s2 += __shfl_xor(s2, off, 64);
    }
    __shared__ float red[8];
    if (lane == 0) { red[wave] = s; red[4 + wave] = s2; }
    __syncthreads();
    s  = red[0] + red[1] + red[2] + red[3];
    s2 = red[4] + red[5] + red[6] + red[7];
    const float inv_n = 1.0f / 1024.0f;
    float mean = s * inv_n;
    float var  = s2 * inv_n - mean * mean;
    float rstd = rsqrtf(var + 1e-5f);
    float gv[4], bv[4];
    if (isf) {
        float4 gg = *(const float4*)((const float*)g + tid * 4);
        float4 bo = *(const float4*)((const float*)bb + tid * 4);
        gv[0] = gg.x; gv[1] = gg.y; gv[2] = gg.z; gv[3] = gg.w;
        bv[0] = bo.x; bv[1] = bo.y; bv[2] = bo.z; bv[3] = bo.w;
    } else {
        uint2 go = *(const uint2*)((const u16*)g + tid * 4);
        uint2 bo = *(const uint2*)((const u16*)bb + tid * 4);
        gv[0] = b2f((u16)(go.x & 0xffff)); gv[1] = b2f((u16)(go.x >> 16));
        gv[2] = b2f((u16)(go.y & 0xffff)); gv[3] = b2f((u16)(go.y >> 16));
        bv[0] = b2f((u16)(bo.x & 0xffff)); bv[1] = b2f((u16)(bo.x >> 16));
        bv[2] = b2f((u16)(bo.y & 0xffff)); bv[3] = b2f((u16)(bo.y >> 16));
    }
    float xa[4] = { xv.x, xv.y, xv.z, xv.w };
    u16 o[4];
#pragma unroll
    for (int j = 0; j < 4; j++)
        o[j] = f2b((xa[j] - mean) * rstd * gv[j] + bv[j]);
    uint2 pk;
    pk.x = (unsigned)o[0] | ((unsigned)o[1] << 16);
    pk.y = (unsigned)o[2] | ((unsigned)o[3] << 16);
    *(uint2*)(out + base) = pk;
}

// ------------------------------------------------------------ GEMM: C[M,N] = A[M,K] * BT[N,K]^T + epilogue
// BM = MT*32, BN = NT*32; 4 waves in 2x2. Staging via global_load_lds 16B/lane
// in 4KB chunks; row-major [row][BK] with col-block swizzle
//   phys = (log + SWZ(row)) & CBM,  SWZ(r) = r    for BK=64 (measured: 0 conflicts)
//                                   SWZ(r) = r>>1 for BK=32 (measured r9: 0 conflicts)
// XCD-aware bijective block swizzle (T1): FETCH_SIZE = ideal (measured r4).
// Counted-vmcnt pipeline (T3/T4), DEPTH buffers: vmcnt never drains to 0
// mid-loop. MEASURED r7: 2,2/BK64/D2 = 44us @ 4096x1024x4096 (from 57).
// LDS-OCCUPANCY MODEL (r7/r9/r10): schedulable LDS behaves as ~128KB/CU:
//   32KB -> 3-4 blk, 48KB -> 2 blk, 64KB -> 2 blk.
// 4,4 PIPELINE LADDER (measured): BK64/D1=57; BK32/D2=65; BK64/D2=77;
//   BK32/D3=90 -> 4,4 cannot pipeline within LDS budget. r12: run the big
//   GEMMs as 2,2/BK64/D2 instead (same FLOPs & K-step count as the proven
//   44us down-proj; B fits L3 so extra panel re-reads don't hit HBM).
// MODE 0: bf16 out (+bias); 1: bf16 gelu(acc+bias); 2: f32 acc+bias+res; 3: final (bf16 or f32 by flag)
template <int MODE, int MT, int NT, int BK, int MINW, int DEPTH>
__global__ __launch_bounds__(256, MINW) void gemm_kernel(const u16* __restrict__ A,
                                                         const u16* __restrict__ BT,
                                                         const void* __restrict__ bias,
                                                         const float* __restrict__ res,
                                                         void* __restrict__ Cout,
                                                         int M, int N, int K,
                                                         const int* __restrict__ flag) {
    constexpr int CB  = BK / 8;          // 16B col-blocks per row
    constexpr int CBM = CB - 1;
    constexpr int RPC = 2048 / BK;       // rows per 4KB chunk
    constexpr int NCA = (MT * 32) / RPC; // 4KB chunks in A tile
    constexpr int NCB = (NT * 32) / RPC;
    constexpr int NB  = (DEPTH > 1) ? DEPTH : 1;
    __shared__ __align__(16) u16 lsA[NB][MT * 32 * BK];
    __shared__ __align__(16) u16 lsB[NB][NT * 32 * BK];
    const int tid = threadIdx.x;
    const int lane = tid & 63;
    const int wave = tid >> 6;
    const int wm = (wave >> 1) * (MT * 16);
    const int wn = (wave & 1) * (NT * 16);

    // swizzle row-shift: see header comment
    auto swz = [](int r) { return (BK == 32) ? (r >> 1) : r; };

    // XCD-aware bijective block swizzle (nwg % 8 == 0 for all launch shapes)
    int bx = blockIdx.x, by = blockIdx.y;
    {
        int nwg = (int)(gridDim.x * gridDim.y);
        if ((nwg & 7) == 0) {
            int bid = by * gridDim.x + bx;
            int wg = (bid & 7) * (nwg >> 3) + (bid >> 3);
            bx = wg % gridDim.x;
            by = wg / gridDim.x;
        }
    }
    const int bm = by * (MT * 32);
    const int bn = bx * (NT * 32);
    const int l16 = lane & 15;
    const int lq = lane >> 4;
    const bool isf = (*flag != 0);

    floatx4 acc[MT][NT] = {};

    const int r_in = tid / CB;                            // row within chunk
    const int cb_log = ((tid & CBM) - swz(r_in)) & CBM;   // lands at phys = tid & CBM
    const int gcol = cb_log * 8;

    const u16* gA[NCA];
#pragma unroll
    for (int c = 0; c < NCA; c++) {
        int rr = bm + c * RPC + r_in; if (rr >= M) rr = M - 1;  // clamp: finite, never stored
        gA[c] = A + (size_t)rr * K + gcol;
    }
    const u16* gB[NCB];
#pragma unroll
    for (int c = 0; c < NCB; c++) {
        int rr = bn + c * RPC + r_in; if (rr >= N) rr = N - 1;
        gB[c] = BT + (size_t)rr * K + gcol;
    }

    auto stage = [&](int bf, int k0) {
#pragma unroll
        for (int c = 0; c < NCA; c++)
            __builtin_amdgcn_global_load_lds((g_void*)(gA[c] + k0),
                                             (l_void*)(&lsA[bf][c * 2048 + tid * 8]), 16, 0, 0);
#pragma unroll
        for (int c = 0; c < NCB; c++)
            __builtin_amdgcn_global_load_lds((g_void*)(gB[c] + k0),
                                             (l_void*)(&lsB[bf][c * 2048 + tid * 8]), 16, 0, 0);
    };

    auto compute = [&](int bf) {
#pragma unroll
        for (int ki = 0; ki < BK / 32; ki++) {
            short8 af[MT], bfr[NT];
#pragma unroll
            for (int mi = 0; mi < MT; mi++) {
                int ra = wm + mi * 16 + l16;
                af[mi] = *(const short8*)&lsA[bf][ra * BK + ((ki * 4 + lq + swz(ra)) & CBM) * 8];
            }
#pragma unroll
            for (int ni = 0; ni < NT; ni++) {
                int rb = wn + ni * 16 + l16;
                bfr[ni] = *(const short8*)&lsB[bf][rb * BK + ((ki * 4 + lq + swz(rb)) & CBM) * 8];
            }
#pragma unroll
            for (int mi = 0; mi < MT; mi++)
#pragma unroll
                for (int ni = 0; ni < NT; ni++)
                    acc[mi][ni] = __builtin_amdgcn_mfma_f32_16x16x32_bf16(af[mi], bfr[ni], acc[mi][ni], 0, 0, 0);
        }
    };

    if constexpr (DEPTH > 1) {
        constexpr int L = NCA + NCB;         // VMEM insts per stage per thread
        static_assert(L == 4, "counted-vmcnt literals below assume 4 loads/stage");
        const int nk = K / BK;               // nk >= DEPTH for all launch shapes
#pragma unroll
        for (int d = 0; d < DEPTH; ++d)
            stage(d, d * BK);
        int cur = 0;
        for (int t = 0; t < nk; t++) {
            const int rem = nk - 1 - t;      // tiles still in flight beyond t
            if (DEPTH >= 3 && rem >= 2)      asm volatile("s_waitcnt vmcnt(8)" ::: "memory");
            else if (rem >= 1)               asm volatile("s_waitcnt vmcnt(4)" ::: "memory");
            else                             asm volatile("s_waitcnt vmcnt(0)" ::: "memory");
            __builtin_amdgcn_s_barrier();
            compute(cur);
            __builtin_amdgcn_s_barrier();    // all waves done reading buf[cur]
            if (t + DEPTH < nk) stage(cur, (t + DEPTH) * BK);
            cur = (cur + 1 == NB) ? 0 : cur + 1;
        }
    } else {
        for (int k0 = 0; k0 < K; k0 += BK) {
            stage(0, k0);
            __syncthreads();
            compute(0);
            __syncthreads();
        }
    }

#pragma unroll
    for (int mi = 0; mi < MT; mi++) {
#pragma unroll
        for (int ni = 0; ni < NT; ni++) {
            int col = bn + wn + ni * 16 + l16;
            float bv = 0.0f;
            if (bias) bv = isf ? ((const float*)bias)[col] : b2f(((const u16*)bias)[col]);
#pragma unroll
            for (int r = 0; r < 4; r++) {
                int row = bm + wm + mi * 16 + lq * 4 + r;
                if (row < M) {
                    float v = acc[mi][ni][r] + bv;
                    size_t idx = (size_t)row * N + col;
                    if (MODE == 1) v = gelu_exact(v);
                    if (MODE == 2 || MODE == 3) v += res[idx];
                    if (MODE == 2)       ((float*)Cout)[idx] = v;
                    else if (MODE == 3) { if (isf) ((float*)Cout)[idx] = v; else ((u16*)Cout)[idx] = f2b(v); }
                    else                 ((u16*)Cout)[idx] = f2b(v);
                }
            }
        }
    }
}

// ------------------------------------------------------------ MFMA flash attention v3: 128 q-rows/block
// No online rescaling (scores bounded: |s*scale| << 80 -> exp2 overflow-safe).
// Q/K DMA-staged (swizzled stride-64); Vt XOR-swizzled; wave owns 2 strips of 16 rows.
// grid (T/128, B*16), 4 waves. cexp = scale*log2(e).
// XCD swizzle clusters the 8 q-tile blocks sharing one (b,h)'s K/V onto one XCD.
// T14 async-stage split (r11, kept): V loads for tile t+1 issued at the bottom
// of tile t; bottom barrier is counted vmcnt(2) + raw s_barrier.
__global__ __launch_bounds__(256, 2) void attn_mfma_kernel(const u16* __restrict__ q,
                                                           const u16* __restrict__ k,
                                                           const u16* __restrict__ v,
                                                           u16* __restrict__ o,
                                                           int T, int S, int ldq, int ldkv,
                                                           float cexp) {
    const int E = 1024;
    int bx = blockIdx.x, byy = blockIdx.y;
    {
        int nwg = (int)(gridDim.x * gridDim.y);
        if ((nwg & 7) == 0) {
            int bid = byy * gridDim.x + bx;
            int wg = (bid & 7) * (nwg >> 3) + (bid >> 3);
            bx = wg % gridDim.x;
            byy = wg / gridDim.x;
        }
    }
    const int b = byy >> 4, h = byy & 15;
    const int tid = threadIdx.x, wave = tid >> 6, lane = tid & 63;
    const int l16 = lane & 15, lq = lane >> 4;

    __shared__ __align__(16) u16 Qs[128 * 64];       // 16 KB
    __shared__ __align__(16) u16 Ks[64 * 64];        // 8 KB
    __shared__ __align__(16) u16 Vt[64 * 72];        // 9 KB
    __shared__ __align__(16) u16 Ps[4][16 * 72];     // 9 KB

    const int q0 = bx * 128;
    const int r8 = tid >> 3;
    const int cb_log = ((tid & 7) - r8) & 7;
    const int rv = tid >> 2, cv = (tid & 3) * 16;
    const int cbv = ((rv >> 3) ^ (tid & 3)) & 7;

    // stage Q (128 rows; T % 128 == 0)
#pragma unroll
    for (int j = 0; j < 4; j++) {
        int row = q0 + j * 32 + r8;
        __builtin_amdgcn_global_load_lds((g_void*)(q + (size_t)(b * T + row) * ldq + h * 64 + cb_log * 8),
                                         (l_void*)(Qs + j * 2048 + tid * 8), 16, 0, 0);
    }
    __syncthreads();

    short8 af[2][2];
#pragma unroll
    for (int j = 0; j < 2; j++) {
        int qr = j * 64 + wave * 16 + l16;
        af[j][0] = *(const short8*)&Qs[qr * 64 + ((lq + qr) & 7) * 8];
        af[j][1] = *(const short8*)&Qs[qr * 64 + ((lq + 4 + qr) & 7) * 8];
    }

    float lsum[2][4] = {};
    floatx4 oacc[2][4] = {};

    const int ntiles = (S + 63) >> 6;
    // prologue: V regs for tile 0
    uint4 vr0, vr1;
    {
        int sr = rv; if (sr >= S) sr = S - 1;
        const u16* vsrc = v + (size_t)(b * S + sr) * ldkv + h * 64 + cv;
        vr0 = *(const uint4*)vsrc;
        vr1 = *(const uint4*)(vsrc + 8);
    }
    for (int t = 0; t < ntiles; t++) {
        const int s0 = t * 64;
        __syncthreads();   // all waves done reading Ks/Vt of t-1
#pragma unroll
        for (int j = 0; j < 2; j++) {
            int srow = s0 + j * 32 + r8; if (srow >= S) srow = S - 1;
            __builtin_amdgcn_global_load_lds((g_void*)(k + (size_t)(b * S + srow) * ldkv + h * 64 + cb_log * 8),
                                             (l_void*)(Ks + j * 2048 + tid * 8), 16, 0, 0);
        }
        {
            // write tile t's V regs (loaded last iteration / prologue)
            const u16* vp = (const u16*)&vr0;
#pragma unroll
            for (int j = 0; j < 8; j++)
                Vt[(cv + j) * 72 + cbv * 8 + (rv & 7)] = vp[j];
            vp = (const u16*)&vr1;
#pragma unroll
            for (int j = 0; j < 8; j++)
                Vt[(cv + 8 + j) * 72 + cbv * 8 + (rv & 7)] = vp[j];
        }
        if (t + 1 < ntiles) {
            // early-issue V loads for t+1 (T14): consumed at next iteration's write
            int sr = s0 + 64 + rv; if (sr >= S) sr = S - 1;
            const u16* vsrc = v + (size_t)(b * S + sr) * ldkv + h * 64 + cv;
            vr0 = *(const uint4*)vsrc;
            vr1 = *(const uint4*)(vsrc + 8);
            // oldest 2 outstanding = this tile's K DMA -> must land; newest 2 = V prefetch, stay in flight
            asm volatile("s_waitcnt vmcnt(2) lgkmcnt(0)" ::: "memory");
        } else {
            asm volatile("s_waitcnt vmcnt(0) lgkmcnt(0)" ::: "memory");
        }
        __builtin_amdgcn_s_barrier();

        const bool tail = (s0 + 64 > S);
#pragma unroll
        for (int j = 0; j < 2; j++) {
            // scores for strip j
            floatx4 sc[4];
#pragma unroll
            for (int nt = 0; nt < 4; nt++) {
                int krow = nt * 16 + l16;
                short8 bf0 = *(const short8*)&Ks[krow * 64 + ((lq + krow) & 7) * 8];
                short8 bf1 = *(const short8*)&Ks[krow * 64 + ((lq + 4 + krow) & 7) * 8];
                floatx4 z = {};
                z = __builtin_amdgcn_mfma_f32_16x16x32_bf16(af[j][0], bf0, z, 0, 0, 0);
                z = __builtin_amdgcn_mfma_f32_16x16x32_bf16(af[j][1], bf1, z, 0, 0, 0);
                sc[nt] = z;
            }
#pragma unroll
            for (int nt = 0; nt < 4; nt++) {
                bool colv = !tail || (s0 + nt * 16 + l16 < S);
#pragma unroll
                for (int r = 0; r < 4; r++) {
                    float p = exp2f(sc[nt][r] * cexp);
                    p = colv ? p : 0.0f;
                    lsum[j][r] += p;
                    Ps[wave][(lq * 4 + r) * 72 + nt * 16 + l16] = f2b(p);
                }
            }
            short8 av0 = *(const short8*)&Ps[wave][l16 * 72 + lq * 8];
            short8 av1 = *(const short8*)&Ps[wave][l16 * 72 + 32 + lq * 8];
#pragma unroll
            for (int dt = 0; dt < 4; dt++) {
                int d = dt * 16 + l16;
                short8 bv0 = *(const short8*)&Vt[d * 72 + ((lq ^ dt) & 7) * 8];
                short8 bv1 = *(const short8*)&Vt[d * 72 + (((4 + lq) ^ dt) & 7) * 8];
                oacc[j][dt] = __builtin_amdgcn_mfma_f32_16x16x32_bf16(av0, bv0, oacc[j][dt], 0, 0, 0);
                oacc[j][dt] = __builtin_amdgcn_mfma_f32_16x16x32_bf16(av1, bv1, oacc[j][dt], 0, 0, 0);
            }
        }
    }

#pragma unroll
    for (int j = 0; j < 2; j++)
#pragma unroll
        for (int r = 0; r < 4; r++) {
#pragma unroll
            for (int off = 1; off < 16; off <<= 1)
                lsum[j][r] += __shfl_xor(lsum[j][r], off, 64);
        }

#pragma unroll
    for (int j = 0; j < 2; j++)
#pragma unroll
        for (int r = 0; r < 4; r++) {
            float inv = 1.0f / lsum[j][r];
            int row = q0 + j * 64 + wave * 16 + lq * 4 + r;
            u16* dst = o + (size_t)(b * T + row) * E + h * 64 + l16;
#pragma unroll
            for (int dt = 0; dt < 4; dt++)
                dst[dt * 16] = f2b(oacc[j][dt][r] * inv);
        }
}

// ------------------------------------------------------------ host
extern "C" void kernel_launch(void* const* d_in, const int* in_sizes, int n_in,
                              void* d_out, int out_size, void* d_ws, size_t ws_size,
                              hipStream_t stream) {
    const void* x_in = d_in[0];
    const void* ctx  = d_in[1];
    const void* sq_w = d_in[2];
    const void* sk_w = d_in[3];
    const void* sv_w = d_in[4];
    const void* so_w = d_in[5];
    const void* so_b = d_in[6];
    const void* cq_w = d_in[7];
    const void* ck_w = d_in[8];
    const void* cv_w = d_in[9];
    const void* co_w = d_in[10];
    const void* co_b = d_in[11];
    const void* n1_g = d_in[12];
    const void* n1_b = d_in[13];
    const void* n2_g = d_in[14];
    const void* n2_b = d_in[15];
    const void* n3_g = d_in[16];
    const void* n3_b = d_in[17];
    const void* n4_g = d_in[18];
    const void* n4_b = d_in[19];
    const void* f1_w1 = d_in[20];
    const void* f1_b1 = d_in[21];
    const void* f1_w2 = d_in[22];
    const void* f1_b2 = d_in[23];
    const void* f2_w1 = d_in[24];
    const void* f2_b1 = d_in[25];
    const void* f2_w2 = d_in[26];
    const void* f2_b2 = d_in[27];

    const int B = 4, T = 1024, H = 1024, FF = 4096, CD = 768, S = 77;
    const int BT_ = B * T;   // 4096
    const int BS_ = B * S;   // 308

    char* ws = (char*)d_ws;
    size_t off = 0;
    auto alloc = [&](size_t bytes) { char* p = ws + off; off += (bytes + 255) & ~(size_t)255; return p; };
    int*   flag = (int*)alloc(256);
    u16*   ctxb = (u16*)alloc((size_t)BS_ * CD * 2);
    float* xcur = (float*)alloc((size_t)BT_ * H * 4);
    const size_t MEL = 1024 * 1024;
    u16* wqkv = (u16*)alloc(3 * MEL * 2);
    u16* wso  = (u16*)alloc(MEL * 2);
    u16* wcq  = (u16*)alloc(MEL * 2);
    u16* wckv = (u16*)alloc((size_t)2 * H * CD * 2);
    u16* wco  = (u16*)alloc(MEL * 2);
    u16* wf1a = (u16*)alloc((size_t)H * FF * 2);
    u16* wf1b = (u16*)alloc((size_t)H * FF * 2);
    u16* wf2a = (u16*)alloc((size_t)H * FF * 2);
    u16* wf2b = (u16*)alloc((size_t)H * FF * 2);
    u16* U    = (u16*)alloc((size_t)40 * 1024 * 1024);
    (void)ws_size; (void)n_in; (void)in_sizes; (void)out_size;

    const size_t AEL = (size_t)BT_ * H;
    u16* lnb  = U;
    u16* qkvb = U + AEL;
    u16* ob   = U + 4 * AEL;
    u16* hb   = U + AEL;
    u16* qb   = U + AEL;
    u16* kvb  = U + 2 * AEL;

    TPack tp;
    auto ent = [&](int i, const void* src, u16* dst, int R, int C) {
        tp.e[i] = TEnt{ src, dst, R, C, C / 64, (C / 64) * (R / 64) };
    };
    ent(0,  sq_w, wqkv,           H,  H);
    ent(1,  sk_w, wqkv + MEL,     H,  H);
    ent(2,  sv_w, wqkv + 2 * MEL, H,  H);
    ent(3,  so_w, wso,            H,  H);
    ent(4,  cq_w, wcq,            H,  H);
    ent(5,  ck_w, wckv,           CD, H);
    ent(6,  cv_w, wckv + (size_t)H * CD, CD, H);
    ent(7,  co_w, wco,            H,  H);
    ent(8,  f1_w1, wf1a,          H,  FF);
    ent(9,  f1_w2, wf1b,          FF, H);
    ent(10, f2_w1, wf2a,          H,  FF);
    ent(11, f2_w2, wf2b,          FF, H);

    const dim3 g_qkv22(3072 / 64, BT_ / 64);         // 48x64 = 3072 blocks, 64x64 tiles
    const dim3 g_ff22(FF / 64, BT_ / 64);            // 64x64 = 4096 blocks
    const dim3 g_n1024(H / 64, BT_ / 64);            // 1024 blocks
    const dim3 g_ckv(2048 / 64, (BS_ + 63) / 64);
    const dim3 attn_grid(T / 128, B * 16);
    const float cexp = 0.125f * 1.4426950408889634f;

    sniff_kernel<<<1, 64, 0, stream>>>((const u16*)x_in, flag);
    cvt_bf_kernel<<<(BS_ * CD / 4 + 255) / 256, 256, 0, stream>>>(ctx, ctxb, BS_ * CD / 4, flag);
    transpose_batch_kernel<<<dim3(1024, 12), 256, 0, stream>>>(tp, flag);

    // ---- self-attention block
    ln_kernel<<<BT_, 256, 0, stream>>>(x_in, xcur, n1_g, n1_b, lnb, flag, 1);
    gemm_kernel<0, 2, 2, 64, 4, 2><<<g_qkv22, 256, 0, stream>>>(lnb, wqkv, nullptr, nullptr, qkvb, BT_, 3072, H, flag);
    attn_mfma_kernel<<<attn_grid, 256, 0, stream>>>(qkvb, qkvb + 1024, qkvb + 2048, ob, T, T, 3072, 3072, cexp);
    gemm_kernel<2, 2, 2, 64, 4, 2><<<g_n1024, 256, 0, stream>>>(ob, wso, so_b, xcur, xcur, BT_, H, H, flag);

    // ---- FFN 1
    ln_kernel<<<BT_, 256, 0, stream>>>(xcur, nullptr, n2_g, n2_b, lnb, flag, 0);
    gemm_kernel<1, 2, 2, 64, 4, 2><<<g_ff22, 256, 0, stream>>>(lnb, wf1a, f1_b1, nullptr, hb, BT_, FF, H, flag);
    gemm_kernel<2, 2, 2, 64, 4, 2><<<g_n1024, 256, 0, stream>>>(hb, wf1b, f1_b2, xcur, xcur, BT_, H, FF, flag);

    // ---- cross-attention block
    ln_kernel<<<BT_, 256, 0, stream>>>(xcur, nullptr, n3_g, n3_b, lnb, flag, 0);
    gemm_kernel<0, 2, 2, 64, 4, 2><<<g_n1024, 256, 0, stream>>>(lnb, wcq, nullptr, nullptr, qb, BT_, H, H, flag);
    gemm_kernel<0, 2, 2, 64, 4, 2><<<g_ckv, 256, 0, stream>>>(ctxb, wckv, nullptr, nullptr, kvb, BS_, 2048, CD, flag);
    attn_mfma_kernel<<<attn_grid, 256, 0, stream>>>(qb, kvb, kvb + 1024, ob, T, S, 1024, 2048, cexp);
    gemm_kernel<2, 2, 2, 64, 4, 2><<<g_n1024, 256, 0, stream>>>(ob, wco, co_b, xcur, xcur, BT_, H, H, flag);

    // ---- FFN 2 (final output -> d_out)
    ln_kernel<<<BT_, 256, 0, stream>>>(xcur, nullptr, n4_g, n4_b, lnb, flag, 0);
    gemm_kernel<1, 2, 2, 64, 4, 2><<<g_ff22, 256, 0, stream>>>(lnb, wf2a, f2_b1, nullptr, hb, BT_, FF, H, flag);
    gemm_kernel<3, 2, 2, 64, 4, 2><<<g_n1024, 256, 0, stream>>>(hb, wf2b, f2_b2, xcur, d_out, BT_, H, FF, flag);
}

// Round 13
// 618.647 us; speedup vs baseline: 1.0662x; 1.0662x over previous
//
#include <hip/hip_runtime.h>
#include <cstdint>
#include <cstddef>

typedef unsigned short u16;
typedef __attribute__((ext_vector_type(8))) short short8;
typedef __attribute__((ext_vector_type(4))) float floatx4;

typedef const __attribute__((address_space(1))) void g_void;
typedef __attribute__((address_space(3))) void l_void;

__device__ __forceinline__ float b2f(u16 u) {
    union { unsigned int i; float f; } v; v.i = ((unsigned int)u) << 16; return v.f;
}
__device__ __forceinline__ u16 f2b(float f) {
    union { float f; unsigned int i; } v; v.f = f;
    unsigned int x = v.i;
    return (u16)((x + 0x7fffu + ((x >> 16) & 1u)) >> 16);
}
__device__ __forceinline__ float gelu_exact(float x) {
    return 0.5f * x * (1.0f + erff(x * 0.70710678118654752440f));
}

// ------------------------------------------------------------ dtype sniff
__global__ void sniff_kernel(const u16* __restrict__ x, int* __restrict__ flag) {
    int lane = threadIdx.x;
    int sane = 0;
    for (int i = lane * 2; i < 4096; i += 128) {
        int e = (x[i] >> 7) & 0xff;
        if (e >= 100 && e <= 140) sane++;
    }
#pragma unroll
    for (int off = 32; off; off >>= 1) sane += __shfl_xor(sane, off, 64);
    if (lane == 0) *flag = (sane * 2 >= 2048) ? 0 : 1;
}

// ------------------------------------------------------------ any -> bf16 canonical (ctx)
__global__ __launch_bounds__(256) void cvt_bf_kernel(const void* __restrict__ in,
                                                     u16* __restrict__ out, int n4,
                                                     const int* __restrict__ flag) {
    int i = blockIdx.x * 256 + threadIdx.x;
    if (i >= n4) return;
    bool isf = (*flag != 0);
    uint2 pk;
    if (isf) {
        float4 v = ((const float4*)in)[i];
        pk.x = (unsigned)f2b(v.x) | ((unsigned)f2b(v.y) << 16);
        pk.y = (unsigned)f2b(v.z) | ((unsigned)f2b(v.w) << 16);
    } else {
        pk = ((const uint2*)in)[i];
    }
    ((uint2*)out)[i] = pk;
}

// ------------------------------------------------------------ batched transpose+cast: 12 weights in one launch
// 64x64 tiles, 256 threads, 16 elem/thread, fully vectorized (r6: removed the
// scalar-2B version that ran at 21% HBM). LDS row stride 66 u16 = 33 dwords.
struct TEnt { const void* src; u16* dst; int R, C, tiles_x, tiles; };
struct TPack { TEnt e[12]; };

__global__ __launch_bounds__(256) void transpose_batch_kernel(TPack p, const int* __restrict__ flag) {
    TEnt e = p.e[blockIdx.y];
    if ((int)blockIdx.x >= e.tiles) return;
    __shared__ u16 t[64 * 66];
    const bool isf = (*flag != 0);
    const int tid = threadIdx.x;
    const int c0 = (blockIdx.x % e.tiles_x) * 64;
    const int r0 = (blockIdx.x / e.tiles_x) * 64;
    {
        const int row = tid >> 2, cs = tid & 3;          // row 0..63, 16-col seg 0..3
        u16 vv[16];
        if (isf) {
            const float* s = (const float*)e.src + (size_t)(r0 + row) * e.C + c0 + cs * 16;
#pragma unroll
            for (int q = 0; q < 4; q++) {
                float4 f = ((const float4*)s)[q];
                vv[q * 4 + 0] = f2b(f.x); vv[q * 4 + 1] = f2b(f.y);
                vv[q * 4 + 2] = f2b(f.z); vv[q * 4 + 3] = f2b(f.w);
            }
        } else {
            const u16* s = (const u16*)e.src + (size_t)(r0 + row) * e.C + c0 + cs * 16;
            uint4 a = ((const uint4*)s)[0];
            uint4 b = ((const uint4*)s)[1];
            const u16* ap = (const u16*)&a;
            const u16* bp = (const u16*)&b;
#pragma unroll
            for (int q = 0; q < 8; q++) { vv[q] = ap[q]; vv[8 + q] = bp[q]; }
        }
        u16* dl = t + row * 66 + cs * 16;                // byte addr row*132+cs*32: 4B-aligned
#pragma unroll
        for (int q = 0; q < 8; q++)
            ((unsigned*)dl)[q] = (unsigned)vv[2 * q] | ((unsigned)vv[2 * q + 1] << 16);
    }
    __syncthreads();
    {
        const int cc2 = tid >> 3, rs = tid & 7;          // dst col pair 0..31, 8-row seg 0..7
        u16 lo[8], hi[8];
#pragma unroll
        for (int j = 0; j < 8; j++) {
            unsigned w = *(const unsigned*)(t + (size_t)(rs * 8 + j) * 66 + cc2 * 2);
            lo[j] = (u16)w; hi[j] = (u16)(w >> 16);
        }
        uint4 pl, ph;
        pl.x = (unsigned)lo[0] | ((unsigned)lo[1] << 16); pl.y = (unsigned)lo[2] | ((unsigned)lo[3] << 16);
        pl.z = (unsigned)lo[4] | ((unsigned)lo[5] << 16); pl.w = (unsigned)lo[6] | ((unsigned)lo[7] << 16);
        ph.x = (unsigned)hi[0] | ((unsigned)hi[1] << 16); ph.y = (unsigned)hi[2] | ((unsigned)hi[3] << 16);
        ph.z = (unsigned)hi[4] | ((unsigned)hi[5] << 16); ph.w = (unsigned)hi[6] | ((unsigned)hi[7] << 16);
        u16* d0 = e.dst + (size_t)(c0 + cc2 * 2) * e.R + r0 + rs * 8;
        *(uint4*)d0 = pl;
        *(uint4*)(d0 + e.R) = ph;
    }
}

// ------------------------------------------------------------ LayerNorm, row=1024
// raw=0: x is fp32[rows][1024]. raw=1: x is the network input (dtype per flag);
// additionally writes the fp32 copy to xout (residual stream init).
__global__ __launch_bounds__(256) void ln_kernel(const void* __restrict__ x,
                                                 float* __restrict__ xout,
                                                 const void* __restrict__ g,
                                                 const void* __restrict__ bb,
                                                 u16* __restrict__ out,
                                                 const int* __restrict__ flag,
                                                 int raw) {
    const int row = blockIdx.x;
    const int tid = threadIdx.x;
    const int lane = tid & 63, wave = tid >> 6;
    bool isf = (*flag != 0);
    size_t base = (size_t)row * 1024 + tid * 4;
    float4 xv;
    if (raw && !isf) {
        uint2 w = ((const uint2*)x)[base >> 2];
        xv.x = b2f((u16)(w.x & 0xffff)); xv.y = b2f((u16)(w.x >> 16));
        xv.z = b2f((u16)(w.y & 0xffff)); xv.w = b2f((u16)(w.y >> 16));
    } else {
        xv = ((const float4*)x)[base >> 2];
    }
    if (raw) ((float4*)xout)[base >> 2] = xv;
    float s  = xv.x + xv.y + xv.z + xv.w;
    float s2 = xv.x * xv.x + xv.y * xv.y + xv.z * xv.z + xv.w * xv.w;
#pragma unroll
    for (int off = 32; off; off >>= 1) {
        s  += __shfl_xor(s, off, 64);
        s2 += __shfl_xor(s2, off, 64);
    }
    __shared__ float red[8];
    if (lane == 0) { red[wave] = s; red[4 + wave] = s2; }
    __syncthreads();
    s  = red[0] + red[1] + red[2] + red[3];
    s2 = red[4] + red[5] + red[6] + red[7];
    const float inv_n = 1.0f / 1024.0f;
    float mean = s * inv_n;
    float var  = s2 * inv_n - mean * mean;
    float rstd = rsqrtf(var + 1e-5f);
    float gv[4], bv[4];
    if (isf) {
        float4 gg = *(const float4*)((const float*)g + tid * 4);
        float4 bo = *(const float4*)((const float*)bb + tid * 4);
        gv[0] = gg.x; gv[1] = gg.y; gv[2] = gg.z; gv[3] = gg.w;
        bv[0] = bo.x; bv[1] = bo.y; bv[2] = bo.z; bv[3] = bo.w;
    } else {
        uint2 go = *(const uint2*)((const u16*)g + tid * 4);
        uint2 bo = *(const uint2*)((const u16*)bb + tid * 4);
        gv[0] = b2f((u16)(go.x & 0xffff)); gv[1] = b2f((u16)(go.x >> 16));
        gv[2] = b2f((u16)(go.y & 0xffff)); gv[3] = b2f((u16)(go.y >> 16));
        bv[0] = b2f((u16)(bo.x & 0xffff)); bv[1] = b2f((u16)(bo.x >> 16));
        bv[2] = b2f((u16)(bo.y & 0xffff)); bv[3] = b2f((u16)(bo.y >> 16));
    }
    float xa[4] = { xv.x, xv.y, xv.z, xv.w };
    u16 o[4];
#pragma unroll
    for (int j = 0; j < 4; j++)
        o[j] = f2b((xa[j] - mean) * rstd * gv[j] + bv[j]);
    uint2 pk;
    pk.x = (unsigned)o[0] | ((unsigned)o[1] << 16);
    pk.y = (unsigned)o[2] | ((unsigned)o[3] << 16);
    *(uint2*)(out + base) = pk;
}

// ------------------------------------------------------------ GEMM: C[M,N] = A[M,K] * BT[N,K]^T + epilogue
// TPB threads = TPB/64 waves in (WROWS x WCOLS); per-wave frags MT x NT.
// BM = WROWS*MT*16, BN = WCOLS*NT*16. Staging via global_load_lds 16B/lane in
// TPB*16B chunks; row-major [row][BK] with col-block swizzle
//   phys = (log + SWZ(row)) & CBM,  SWZ(r) = r    for BK=64 (measured: 0 conflicts)
//                                   SWZ(r) = r>>1 for BK=32 (measured r9: 0 conflicts)
// XCD-aware bijective block swizzle (T1): FETCH_SIZE = ideal (measured r4).
// Counted-vmcnt pipeline (T3/T4), DEPTH buffers: vmcnt never drains to 0
// mid-loop. MEASURED r7: 64sq/BK64/D2/256t = 44us @ 4096x1024x4096 (from 57).
// LDS-OCCUPANCY MODEL (r7/r9/r10): schedulable LDS behaves as ~128KB/CU:
//   32KB -> 3-4 blk, 48KB -> 2 blk, 64KB -> 2 blk.
// r12 LESSON: shrinking the big-GEMM tile to 64sq quarters arithmetic
//   intensity; L3 absorbed only ~2/3 of panel re-reads (FETCH 53->166MB,
//   57->82us). Keep 128sq tiles for the K=1024 GEMMs.
// r13: 128sq tile with TPB=512 (8 waves 2x4) + D2 @ 64KB: same ideal FETCH
//   as 4,4/D1, but 16 waves/CU (vs 12) AND the counted pipeline.
// MODE 0: bf16 out (+bias); 1: bf16 gelu(acc+bias); 2: f32 acc+bias+res; 3: final (bf16 or f32 by flag)
template <int MODE, int MT, int NT, int BK, int MINW, int DEPTH, int TPB, int WCOLS>
__global__ __launch_bounds__(TPB, MINW) void gemm_kernel(const u16* __restrict__ A,
                                                         const u16* __restrict__ BT,
                                                         const void* __restrict__ bias,
                                                         const float* __restrict__ res,
                                                         void* __restrict__ Cout,
                                                         int M, int N, int K,
                                                         const int* __restrict__ flag) {
    constexpr int WROWS = TPB / 64 / WCOLS;
    constexpr int BM  = WROWS * MT * 16;
    constexpr int BN  = WCOLS * NT * 16;
    constexpr int CB  = BK / 8;          // 16B col-blocks per row
    constexpr int CBM = CB - 1;
    constexpr int CHE = TPB * 8;         // u16 elems per staged chunk (TPB x 16B)
    constexpr int RPC = CHE / BK;        // rows per chunk
    constexpr int NCA = BM / RPC;
    constexpr int NCB = BN / RPC;
    constexpr int NB  = (DEPTH > 1) ? DEPTH : 1;
    __shared__ __align__(16) u16 lsA[NB][BM * BK];
    __shared__ __align__(16) u16 lsB[NB][BN * BK];
    const int tid = threadIdx.x;
    const int lane = tid & 63;
    const int wave = tid >> 6;
    const int wm = (wave / WCOLS) * (MT * 16);
    const int wn = (wave % WCOLS) * (NT * 16);

    // swizzle row-shift: see header comment
    auto swz = [](int r) { return (BK == 32) ? (r >> 1) : r; };

    // XCD-aware bijective block swizzle (nwg % 8 == 0 for all launch shapes)
    int bx = blockIdx.x, by = blockIdx.y;
    {
        int nwg = (int)(gridDim.x * gridDim.y);
        if ((nwg & 7) == 0) {
            int bid = by * gridDim.x + bx;
            int wg = (bid & 7) * (nwg >> 3) + (bid >> 3);
            bx = wg % gridDim.x;
            by = wg / gridDim.x;
        }
    }
    const int bm = by * BM;
    const int bn = bx * BN;
    const int l16 = lane & 15;
    const int lq = lane >> 4;
    const bool isf = (*flag != 0);

    floatx4 acc[MT][NT] = {};

    const int r_in = tid / CB;                            // row within chunk
    const int cb_log = ((tid & CBM) - swz(r_in)) & CBM;   // lands at phys = tid & CBM
    const int gcol = cb_log * 8;

    const u16* gA[NCA];
#pragma unroll
    for (int c = 0; c < NCA; c++) {
        int rr = bm + c * RPC + r_in; if (rr >= M) rr = M - 1;  // clamp: finite, never stored
        gA[c] = A + (size_t)rr * K + gcol;
    }
    const u16* gB[NCB];
#pragma unroll
    for (int c = 0; c < NCB; c++) {
        int rr = bn + c * RPC + r_in; if (rr >= N) rr = N - 1;
        gB[c] = BT + (size_t)rr * K + gcol;
    }

    auto stage = [&](int bf, int k0) {
#pragma unroll
        for (int c = 0; c < NCA; c++)
            __builtin_amdgcn_global_load_lds((g_void*)(gA[c] + k0),
                                             (l_void*)(&lsA[bf][c * CHE + tid * 8]), 16, 0, 0);
#pragma unroll
        for (int c = 0; c < NCB; c++)
            __builtin_amdgcn_global_load_lds((g_void*)(gB[c] + k0),
                                             (l_void*)(&lsB[bf][c * CHE + tid * 8]), 16, 0, 0);
    };

    auto compute = [&](int bf) {
#pragma unroll
        for (int ki = 0; ki < BK / 32; ki++) {
            short8 af[MT], bfr[NT];
#pragma unroll
            for (int mi = 0; mi < MT; mi++) {
                int ra = wm + mi * 16 + l16;
                af[mi] = *(const short8*)&lsA[bf][ra * BK + ((ki * 4 + lq + swz(ra)) & CBM) * 8];
            }
#pragma unroll
            for (int ni = 0; ni < NT; ni++) {
                int rb = wn + ni * 16 + l16;
                bfr[ni] = *(const short8*)&lsB[bf][rb * BK + ((ki * 4 + lq + swz(rb)) & CBM) * 8];
            }
#pragma unroll
            for (int mi = 0; mi < MT; mi++)
#pragma unroll
                for (int ni = 0; ni < NT; ni++)
                    acc[mi][ni] = __builtin_amdgcn_mfma_f32_16x16x32_bf16(af[mi], bfr[ni], acc[mi][ni], 0, 0, 0);
        }
    };

    if constexpr (DEPTH > 1) {
        constexpr int L = NCA + NCB;         // VMEM insts per stage per thread
        static_assert(L == 4, "counted-vmcnt literals below assume 4 loads/stage");
        const int nk = K / BK;               // nk >= DEPTH for all launch shapes
#pragma unroll
        for (int d = 0; d < DEPTH; ++d)
            stage(d, d * BK);
        int cur = 0;
        for (int t = 0; t < nk; t++) {
            const int rem = nk - 1 - t;      // tiles still in flight beyond t
            if (DEPTH >= 3 && rem >= 2)      asm volatile("s_waitcnt vmcnt(8)" ::: "memory");
            else if (rem >= 1)               asm volatile("s_waitcnt vmcnt(4)" ::: "memory");
            else                             asm volatile("s_waitcnt vmcnt(0)" ::: "memory");
            __builtin_amdgcn_s_barrier();
            compute(cur);
            __builtin_amdgcn_s_barrier();    // all waves done reading buf[cur]
            if (t + DEPTH < nk) stage(cur, (t + DEPTH) * BK);
            cur = (cur + 1 == NB) ? 0 : cur + 1;
        }
    } else {
        for (int k0 = 0; k0 < K; k0 += BK) {
            stage(0, k0);
            __syncthreads();
            compute(0);
            __syncthreads();
        }
    }

#pragma unroll
    for (int mi = 0; mi < MT; mi++) {
#pragma unroll
        for (int ni = 0; ni < NT; ni++) {
            int col = bn + wn + ni * 16 + l16;
            float bv = 0.0f;
            if (bias) bv = isf ? ((const float*)bias)[col] : b2f(((const u16*)bias)[col]);
#pragma unroll
            for (int r = 0; r < 4; r++) {
                int row = bm + wm + mi * 16 + lq * 4 + r;
                if (row < M) {
                    float v = acc[mi][ni][r] + bv;
                    size_t idx = (size_t)row * N + col;
                    if (MODE == 1) v = gelu_exact(v);
                    if (MODE == 2 || MODE == 3) v += res[idx];
                    if (MODE == 2)       ((float*)Cout)[idx] = v;
                    else if (MODE == 3) { if (isf) ((float*)Cout)[idx] = v; else ((u16*)Cout)[idx] = f2b(v); }
                    else                 ((u16*)Cout)[idx] = f2b(v);
                }
            }
        }
    }
}

// ------------------------------------------------------------ MFMA flash attention v3: 128 q-rows/block
// No online rescaling (scores bounded: |s*scale| << 80 -> exp2 overflow-safe).
// Q/K DMA-staged (swizzled stride-64); Vt XOR-swizzled; wave owns 2 strips of 16 rows.
// grid (T/128, B*16), 4 waves. cexp = scale*log2(e).
// XCD swizzle clusters the 8 q-tile blocks sharing one (b,h)'s K/V onto one XCD.
// T14 async-stage split (r11, kept): V loads for tile t+1 issued at the bottom
// of tile t; bottom barrier is counted vmcnt(2) + raw s_barrier.
__global__ __launch_bounds__(256, 2) void attn_mfma_kernel(const u16* __restrict__ q,
                                                           const u16* __restrict__ k,
                                                           const u16* __restrict__ v,
                                                           u16* __restrict__ o,
                                                           int T, int S, int ldq, int ldkv,
                                                           float cexp) {
    const int E = 1024;
    int bx = blockIdx.x, byy = blockIdx.y;
    {
        int nwg = (int)(gridDim.x * gridDim.y);
        if ((nwg & 7) == 0) {
            int bid = byy * gridDim.x + bx;
            int wg = (bid & 7) * (nwg >> 3) + (bid >> 3);
            bx = wg % gridDim.x;
            byy = wg / gridDim.x;
        }
    }
    const int b = byy >> 4, h = byy & 15;
    const int tid = threadIdx.x, wave = tid >> 6, lane = tid & 63;
    const int l16 = lane & 15, lq = lane >> 4;

    __shared__ __align__(16) u16 Qs[128 * 64];       // 16 KB
    __shared__ __align__(16) u16 Ks[64 * 64];        // 8 KB
    __shared__ __align__(16) u16 Vt[64 * 72];        // 9 KB
    __shared__ __align__(16) u16 Ps[4][16 * 72];     // 9 KB

    const int q0 = bx * 128;
    const int r8 = tid >> 3;
    const int cb_log = ((tid & 7) - r8) & 7;
    const int rv = tid >> 2, cv = (tid & 3) * 16;
    const int cbv = ((rv >> 3) ^ (tid & 3)) & 7;

    // stage Q (128 rows; T % 128 == 0)
#pragma unroll
    for (int j = 0; j < 4; j++) {
        int row = q0 + j * 32 + r8;
        __builtin_amdgcn_global_load_lds((g_void*)(q + (size_t)(b * T + row) * ldq + h * 64 + cb_log * 8),
                                         (l_void*)(Qs + j * 2048 + tid * 8), 16, 0, 0);
    }
    __syncthreads();

    short8 af[2][2];
#pragma unroll
    for (int j = 0; j < 2; j++) {
        int qr = j * 64 + wave * 16 + l16;
        af[j][0] = *(const short8*)&Qs[qr * 64 + ((lq + qr) & 7) * 8];
        af[j][1] = *(const short8*)&Qs[qr * 64 + ((lq + 4 + qr) & 7) * 8];
    }

    float lsum[2][4] = {};
    floatx4 oacc[2][4] = {};

    const int ntiles = (S + 63) >> 6;
    // prologue: V regs for tile 0
    uint4 vr0, vr1;
    {
        int sr = rv; if (sr >= S) sr = S - 1;
        const u16* vsrc = v + (size_t)(b * S + sr) * ldkv + h * 64 + cv;
        vr0 = *(const uint4*)vsrc;
        vr1 = *(const uint4*)(vsrc + 8);
    }
    for (int t = 0; t < ntiles; t++) {
        const int s0 = t * 64;
        __syncthreads();   // all waves done reading Ks/Vt of t-1
#pragma unroll
        for (int j = 0; j < 2; j++) {
            int srow = s0 + j * 32 + r8; if (srow >= S) srow = S - 1;
            __builtin_amdgcn_global_load_lds((g_void*)(k + (size_t)(b * S + srow) * ldkv + h * 64 + cb_log * 8),
                                             (l_void*)(Ks + j * 2048 + tid * 8), 16, 0, 0);
        }
        {
            // write tile t's V regs (loaded last iteration / prologue)
            const u16* vp = (const u16*)&vr0;
#pragma unroll
            for (int j = 0; j < 8; j++)
                Vt[(cv + j) * 72 + cbv * 8 + (rv & 7)] = vp[j];
            vp = (const u16*)&vr1;
#pragma unroll
            for (int j = 0; j < 8; j++)
                Vt[(cv + 8 + j) * 72 + cbv * 8 + (rv & 7)] = vp[j];
        }
        if (t + 1 < ntiles) {
            // early-issue V loads for t+1 (T14): consumed at next iteration's write
            int sr = s0 + 64 + rv; if (sr >= S) sr = S - 1;
            const u16* vsrc = v + (size_t)(b * S + sr) * ldkv + h * 64 + cv;
            vr0 = *(const uint4*)vsrc;
            vr1 = *(const uint4*)(vsrc + 8);
            // oldest 2 outstanding = this tile's K DMA -> must land; newest 2 = V prefetch, stay in flight
            asm volatile("s_waitcnt vmcnt(2) lgkmcnt(0)" ::: "memory");
        } else {
            asm volatile("s_waitcnt vmcnt(0) lgkmcnt(0)" ::: "memory");
        }
        __builtin_amdgcn_s_barrier();

        const bool tail = (s0 + 64 > S);
#pragma unroll
        for (int j = 0; j < 2; j++) {
            // scores for strip j
            floatx4 sc[4];
#pragma unroll
            for (int nt = 0; nt < 4; nt++) {
                int krow = nt * 16 + l16;
                short8 bf0 = *(const short8*)&Ks[krow * 64 + ((lq + krow) & 7) * 8];
                short8 bf1 = *(const short8*)&Ks[krow * 64 + ((lq + 4 + krow) & 7) * 8];
                floatx4 z = {};
                z = __builtin_amdgcn_mfma_f32_16x16x32_bf16(af[j][0], bf0, z, 0, 0, 0);
                z = __builtin_amdgcn_mfma_f32_16x16x32_bf16(af[j][1], bf1, z, 0, 0, 0);
                sc[nt] = z;
            }
#pragma unroll
            for (int nt = 0; nt < 4; nt++) {
                bool colv = !tail || (s0 + nt * 16 + l16 < S);
#pragma unroll
                for (int r = 0; r < 4; r++) {
                    float p = exp2f(sc[nt][r] * cexp);
                    p = colv ? p : 0.0f;
                    lsum[j][r] += p;
                    Ps[wave][(lq * 4 + r) * 72 + nt * 16 + l16] = f2b(p);
                }
            }
            short8 av0 = *(const short8*)&Ps[wave][l16 * 72 + lq * 8];
            short8 av1 = *(const short8*)&Ps[wave][l16 * 72 + 32 + lq * 8];
#pragma unroll
            for (int dt = 0; dt < 4; dt++) {
                int d = dt * 16 + l16;
                short8 bv0 = *(const short8*)&Vt[d * 72 + ((lq ^ dt) & 7) * 8];
                short8 bv1 = *(const short8*)&Vt[d * 72 + (((4 + lq) ^ dt) & 7) * 8];
                oacc[j][dt] = __builtin_amdgcn_mfma_f32_16x16x32_bf16(av0, bv0, oacc[j][dt], 0, 0, 0);
                oacc[j][dt] = __builtin_amdgcn_mfma_f32_16x16x32_bf16(av1, bv1, oacc[j][dt], 0, 0, 0);
            }
        }
    }

#pragma unroll
    for (int j = 0; j < 2; j++)
#pragma unroll
        for (int r = 0; r < 4; r++) {
#pragma unroll
            for (int off = 1; off < 16; off <<= 1)
                lsum[j][r] += __shfl_xor(lsum[j][r], off, 64);
        }

#pragma unroll
    for (int j = 0; j < 2; j++)
#pragma unroll
        for (int r = 0; r < 4; r++) {
            float inv = 1.0f / lsum[j][r];
            int row = q0 + j * 64 + wave * 16 + lq * 4 + r;
            u16* dst = o + (size_t)(b * T + row) * E + h * 64 + l16;
#pragma unroll
            for (int dt = 0; dt < 4; dt++)
                dst[dt * 16] = f2b(oacc[j][dt][r] * inv);
        }
}

// ------------------------------------------------------------ host
extern "C" void kernel_launch(void* const* d_in, const int* in_sizes, int n_in,
                              void* d_out, int out_size, void* d_ws, size_t ws_size,
                              hipStream_t stream) {
    const void* x_in = d_in[0];
    const void* ctx  = d_in[1];
    const void* sq_w = d_in[2];
    const void* sk_w = d_in[3];
    const void* sv_w = d_in[4];
    const void* so_w = d_in[5];
    const void* so_b = d_in[6];
    const void* cq_w = d_in[7];
    const void* ck_w = d_in[8];
    const void* cv_w = d_in[9];
    const void* co_w = d_in[10];
    const void* co_b = d_in[11];
    const void* n1_g = d_in[12];
    const void* n1_b = d_in[13];
    const void* n2_g = d_in[14];
    const void* n2_b = d_in[15];
    const void* n3_g = d_in[16];
    const void* n3_b = d_in[17];
    const void* n4_g = d_in[18];
    const void* n4_b = d_in[19];
    const void* f1_w1 = d_in[20];
    const void* f1_b1 = d_in[21];
    const void* f1_w2 = d_in[22];
    const void* f1_b2 = d_in[23];
    const void* f2_w1 = d_in[24];
    const void* f2_b1 = d_in[25];
    const void* f2_w2 = d_in[26];
    const void* f2_b2 = d_in[27];

    const int B = 4, T = 1024, H = 1024, FF = 4096, CD = 768, S = 77;
    const int BT_ = B * T;   // 4096
    const int BS_ = B * S;   // 308

    char* ws = (char*)d_ws;
    size_t off = 0;
    auto alloc = [&](size_t bytes) { char* p = ws + off; off += (bytes + 255) & ~(size_t)255; return p; };
    int*   flag = (int*)alloc(256);
    u16*   ctxb = (u16*)alloc((size_t)BS_ * CD * 2);
    float* xcur = (float*)alloc((size_t)BT_ * H * 4);
    const size_t MEL = 1024 * 1024;
    u16* wqkv = (u16*)alloc(3 * MEL * 2);
    u16* wso  = (u16*)alloc(MEL * 2);
    u16* wcq  = (u16*)alloc(MEL * 2);
    u16* wckv = (u16*)alloc((size_t)2 * H * CD * 2);
    u16* wco  = (u16*)alloc(MEL * 2);
    u16* wf1a = (u16*)alloc((size_t)H * FF * 2);
    u16* wf1b = (u16*)alloc((size_t)H * FF * 2);
    u16* wf2a = (u16*)alloc((size_t)H * FF * 2);
    u16* wf2b = (u16*)alloc((size_t)H * FF * 2);
    u16* U    = (u16*)alloc((size_t)40 * 1024 * 1024);
    (void)ws_size; (void)n_in; (void)in_sizes; (void)out_size;

    const size_t AEL = (size_t)BT_ * H;
    u16* lnb  = U;
    u16* qkvb = U + AEL;
    u16* ob   = U + 4 * AEL;
    u16* hb   = U + AEL;
    u16* qb   = U + AEL;
    u16* kvb  = U + 2 * AEL;

    TPack tp;
    auto ent = [&](int i, const void* src, u16* dst, int R, int C) {
        tp.e[i] = TEnt{ src, dst, R, C, C / 64, (C / 64) * (R / 64) };
    };
    ent(0,  sq_w, wqkv,           H,  H);
    ent(1,  sk_w, wqkv + MEL,     H,  H);
    ent(2,  sv_w, wqkv + 2 * MEL, H,  H);
    ent(3,  so_w, wso,            H,  H);
    ent(4,  cq_w, wcq,            H,  H);
    ent(5,  ck_w, wckv,           CD, H);
    ent(6,  cv_w, wckv + (size_t)H * CD, CD, H);
    ent(7,  co_w, wco,            H,  H);
    ent(8,  f1_w1, wf1a,          H,  FF);
    ent(9,  f1_w2, wf1b,          FF, H);
    ent(10, f2_w1, wf2a,          H,  FF);
    ent(11, f2_w2, wf2b,          FF, H);

    const dim3 g_qkv(3072 / 128, BT_ / 128);         // 24x32 = 768 blocks, 128x128 tiles
    const dim3 g_ff(FF / 128, BT_ / 128);            // 32x32 = 1024 blocks
    const dim3 g_n1024(H / 64, BT_ / 64);            // 1024 blocks, 64x64 tiles
    const dim3 g_ckv(2048 / 64, (BS_ + 63) / 64);
    const dim3 attn_grid(T / 128, B * 16);
    const float cexp = 0.125f * 1.4426950408889634f;

    sniff_kernel<<<1, 64, 0, stream>>>((const u16*)x_in, flag);
    cvt_bf_kernel<<<(BS_ * CD / 4 + 255) / 256, 256, 0, stream>>>(ctx, ctxb, BS_ * CD / 4, flag);
    transpose_batch_kernel<<<dim3(1024, 12), 256, 0, stream>>>(tp, flag);

    // ---- self-attention block
    ln_kernel<<<BT_, 256, 0, stream>>>(x_in, xcur, n1_g, n1_b, lnb, flag, 1);
    gemm_kernel<0, 4, 2, 64, 4, 2, 512, 4><<<g_qkv, 512, 0, stream>>>(lnb, wqkv, nullptr, nullptr, qkvb, BT_, 3072, H, flag);
    attn_mfma_kernel<<<attn_grid, 256, 0, stream>>>(qkvb, qkvb + 1024, qkvb + 2048, ob, T, T, 3072, 3072, cexp);
    gemm_kernel<2, 2, 2, 64, 4, 2, 256, 2><<<g_n1024, 256, 0, stream>>>(ob, wso, so_b, xcur, xcur, BT_, H, H, flag);

    // ---- FFN 1
    ln_kernel<<<BT_, 256, 0, stream>>>(xcur, nullptr, n2_g, n2_b, lnb, flag, 0);
    gemm_kernel<1, 4, 2, 64, 4, 2, 512, 4><<<g_ff, 512, 0, stream>>>(lnb, wf1a, f1_b1, nullptr, hb, BT_, FF, H, flag);
    gemm_kernel<2, 2, 2, 64, 4, 2, 256, 2><<<g_n1024, 256, 0, stream>>>(hb, wf1b, f1_b2, xcur, xcur, BT_, H, FF, flag);

    // ---- cross-attention block
    ln_kernel<<<BT_, 256, 0, stream>>>(xcur, nullptr, n3_g, n3_b, lnb, flag, 0);
    gemm_kernel<0, 2, 2, 64, 4, 2, 256, 2><<<g_n1024, 256, 0, stream>>>(lnb, wcq, nullptr, nullptr, qb, BT_, H, H, flag);
    gemm_kernel<0, 2, 2, 64, 4, 2, 256, 2><<<g_ckv, 256, 0, stream>>>(ctxb, wckv, nullptr, nullptr, kvb, BS_, 2048, CD, flag);
    attn_mfma_kernel<<<attn_grid, 256, 0, stream>>>(qb, kvb, kvb + 1024, ob, T, S, 1024, 2048, cexp);
    gemm_kernel<2, 2, 2, 64, 4, 2, 256, 2><<<g_n1024, 256, 0, stream>>>(ob, wco, co_b, xcur, xcur, BT_, H, H, flag);

    // ---- FFN 2 (final output -> d_out)
    ln_kernel<<<BT_, 256, 0, stream>>>(xcur, nullptr, n4_g, n4_b, lnb, flag, 0);
    gemm_kernel<1, 4, 2, 64, 4, 2, 512, 4><<<g_ff, 512, 0, stream>>>(lnb, wf2a, f2_b1, nullptr, hb, BT_, FF, H, flag);
    gemm_kernel<3, 2, 2, 64, 4, 2, 256, 2><<<g_n1024, 256, 0, stream>>>(hb, wf2b, f2_b2, xcur, d_out, BT_, H, FF, flag);
}

// Round 14
// 590.214 us; speedup vs baseline: 1.1176x; 1.0482x over previous
//
#include <hip/hip_runtime.h>
#include <cstdint>
#include <cstddef>

typedef unsigned short u16;
typedef __attribute__((ext_vector_type(8))) short short8;
typedef __attribute__((ext_vector_type(4))) float floatx4;

typedef const __attribute__((address_space(1))) void g_void;
typedef __attribute__((address_space(3))) void l_void;

__device__ __forceinline__ float b2f(u16 u) {
    union { unsigned int i; float f; } v; v.i = ((unsigned int)u) << 16; return v.f;
}
__device__ __forceinline__ u16 f2b(float f) {
    union { float f; unsigned int i; } v; v.f = f;
    unsigned int x = v.i;
    return (u16)((x + 0x7fffu + ((x >> 16) & 1u)) >> 16);
}
__device__ __forceinline__ float gelu_exact(float x) {
    return 0.5f * x * (1.0f + erff(x * 0.70710678118654752440f));
}

// ------------------------------------------------------------ dtype sniff
__global__ void sniff_kernel(const u16* __restrict__ x, int* __restrict__ flag) {
    int lane = threadIdx.x;
    int sane = 0;
    for (int i = lane * 2; i < 4096; i += 128) {
        int e = (x[i] >> 7) & 0xff;
        if (e >= 100 && e <= 140) sane++;
    }
#pragma unroll
    for (int off = 32; off; off >>= 1) sane += __shfl_xor(sane, off, 64);
    if (lane == 0) *flag = (sane * 2 >= 2048) ? 0 : 1;
}

// ------------------------------------------------------------ any -> bf16 canonical (ctx)
__global__ __launch_bounds__(256) void cvt_bf_kernel(const void* __restrict__ in,
                                                     u16* __restrict__ out, int n4,
                                                     const int* __restrict__ flag) {
    int i = blockIdx.x * 256 + threadIdx.x;
    if (i >= n4) return;
    bool isf = (*flag != 0);
    uint2 pk;
    if (isf) {
        float4 v = ((const float4*)in)[i];
        pk.x = (unsigned)f2b(v.x) | ((unsigned)f2b(v.y) << 16);
        pk.y = (unsigned)f2b(v.z) | ((unsigned)f2b(v.w) << 16);
    } else {
        pk = ((const uint2*)in)[i];
    }
    ((uint2*)out)[i] = pk;
}

// ------------------------------------------------------------ batched transpose+cast: 12 weights in one launch
// 64x64 tiles, 256 threads, 16 elem/thread, fully vectorized (r6: removed the
// scalar-2B version that ran at 21% HBM). LDS row stride 66 u16 = 33 dwords.
struct TEnt { const void* src; u16* dst; int R, C, tiles_x, tiles; };
struct TPack { TEnt e[12]; };

__global__ __launch_bounds__(256) void transpose_batch_kernel(TPack p, const int* __restrict__ flag) {
    TEnt e = p.e[blockIdx.y];
    if ((int)blockIdx.x >= e.tiles) return;
    __shared__ u16 t[64 * 66];
    const bool isf = (*flag != 0);
    const int tid = threadIdx.x;
    const int c0 = (blockIdx.x % e.tiles_x) * 64;
    const int r0 = (blockIdx.x / e.tiles_x) * 64;
    {
        const int row = tid >> 2, cs = tid & 3;          // row 0..63, 16-col seg 0..3
        u16 vv[16];
        if (isf) {
            const float* s = (const float*)e.src + (size_t)(r0 + row) * e.C + c0 + cs * 16;
#pragma unroll
            for (int q = 0; q < 4; q++) {
                float4 f = ((const float4*)s)[q];
                vv[q * 4 + 0] = f2b(f.x); vv[q * 4 + 1] = f2b(f.y);
                vv[q * 4 + 2] = f2b(f.z); vv[q * 4 + 3] = f2b(f.w);
            }
        } else {
            const u16* s = (const u16*)e.src + (size_t)(r0 + row) * e.C + c0 + cs * 16;
            uint4 a = ((const uint4*)s)[0];
            uint4 b = ((const uint4*)s)[1];
            const u16* ap = (const u16*)&a;
            const u16* bp = (const u16*)&b;
#pragma unroll
            for (int q = 0; q < 8; q++) { vv[q] = ap[q]; vv[8 + q] = bp[q]; }
        }
        u16* dl = t + row * 66 + cs * 16;                // byte addr row*132+cs*32: 4B-aligned
#pragma unroll
        for (int q = 0; q < 8; q++)
            ((unsigned*)dl)[q] = (unsigned)vv[2 * q] | ((unsigned)vv[2 * q + 1] << 16);
    }
    __syncthreads();
    {
        const int cc2 = tid >> 3, rs = tid & 7;          // dst col pair 0..31, 8-row seg 0..7
        u16 lo[8], hi[8];
#pragma unroll
        for (int j = 0; j < 8; j++) {
            unsigned w = *(const unsigned*)(t + (size_t)(rs * 8 + j) * 66 + cc2 * 2);
            lo[j] = (u16)w; hi[j] = (u16)(w >> 16);
        }
        uint4 pl, ph;
        pl.x = (unsigned)lo[0] | ((unsigned)lo[1] << 16); pl.y = (unsigned)lo[2] | ((unsigned)lo[3] << 16);
        pl.z = (unsigned)lo[4] | ((unsigned)lo[5] << 16); pl.w = (unsigned)lo[6] | ((unsigned)lo[7] << 16);
        ph.x = (unsigned)hi[0] | ((unsigned)hi[1] << 16); ph.y = (unsigned)hi[2] | ((unsigned)hi[3] << 16);
        ph.z = (unsigned)hi[4] | ((unsigned)hi[5] << 16); ph.w = (unsigned)hi[6] | ((unsigned)hi[7] << 16);
        u16* d0 = e.dst + (size_t)(c0 + cc2 * 2) * e.R + r0 + rs * 8;
        *(uint4*)d0 = pl;
        *(uint4*)(d0 + e.R) = ph;
    }
}

// ------------------------------------------------------------ LayerNorm, row=1024
// raw=0: x is fp32[rows][1024]. raw=1: x is the network input (dtype per flag);
// additionally writes the fp32 copy to xout (residual stream init).
__global__ __launch_bounds__(256) void ln_kernel(const void* __restrict__ x,
                                                 float* __restrict__ xout,
                                                 const void* __restrict__ g,
                                                 const void* __restrict__ bb,
                                                 u16* __restrict__ out,
                                                 const int* __restrict__ flag,
                                                 int raw) {
    const int row = blockIdx.x;
    const int tid = threadIdx.x;
    const int lane = tid & 63, wave = tid >> 6;
    bool isf = (*flag != 0);
    size_t base = (size_t)row * 1024 + tid * 4;
    float4 xv;
    if (raw && !isf) {
        uint2 w = ((const uint2*)x)[base >> 2];
        xv.x = b2f((u16)(w.x & 0xffff)); xv.y = b2f((u16)(w.x >> 16));
        xv.z = b2f((u16)(w.y & 0xffff)); xv.w = b2f((u16)(w.y >> 16));
    } else {
        xv = ((const float4*)x)[base >> 2];
    }
    if (raw) ((float4*)xout)[base >> 2] = xv;
    float s  = xv.x + xv.y + xv.z + xv.w;
    float s2 = xv.x * xv.x + xv.y * xv.y + xv.z * xv.z + xv.w * xv.w;
#pragma unroll
    for (int off = 32; off; off >>= 1) {
        s  += __shfl_xor(s, off, 64);
        s2 += __shfl_xor(s2, off, 64);
    }
    __shared__ float red[8];
    if (lane == 0) { red[wave] = s; red[4 + wave] = s2; }
    __syncthreads();
    s  = red[0] + red[1] + red[2] + red[3];
    s2 = red[4] + red[5] + red[6] + red[7];
    const float inv_n = 1.0f / 1024.0f;
    float mean = s * inv_n;
    float var  = s2 * inv_n - mean * mean;
    float rstd = rsqrtf(var + 1e-5f);
    float gv[4], bv[4];
    if (isf) {
        float4 gg = *(const float4*)((const float*)g + tid * 4);
        float4 bo = *(const float4*)((const float*)bb + tid * 4);
        gv[0] = gg.x; gv[1] = gg.y; gv[2] = gg.z; gv[3] = gg.w;
        bv[0] = bo.x; bv[1] = bo.y; bv[2] = bo.z; bv[3] = bo.w;
    } else {
        uint2 go = *(const uint2*)((const u16*)g + tid * 4);
        uint2 bo = *(const uint2*)((const u16*)bb + tid * 4);
        gv[0] = b2f((u16)(go.x & 0xffff)); gv[1] = b2f((u16)(go.x >> 16));
        gv[2] = b2f((u16)(go.y & 0xffff)); gv[3] = b2f((u16)(go.y >> 16));
        bv[0] = b2f((u16)(bo.x & 0xffff)); bv[1] = b2f((u16)(bo.x >> 16));
        bv[2] = b2f((u16)(bo.y & 0xffff)); bv[3] = b2f((u16)(bo.y >> 16));
    }
    float xa[4] = { xv.x, xv.y, xv.z, xv.w };
    u16 o[4];
#pragma unroll
    for (int j = 0; j < 4; j++)
        o[j] = f2b((xa[j] - mean) * rstd * gv[j] + bv[j]);
    uint2 pk;
    pk.x = (unsigned)o[0] | ((unsigned)o[1] << 16);
    pk.y = (unsigned)o[2] | ((unsigned)o[3] << 16);
    *(uint2*)(out + base) = pk;
}

// ------------------------------------------------------------ GEMM: C[M,N] = A[M,K] * BT[N,K]^T + epilogue
// BM = MT*32, BN = NT*32; 4 waves in 2x2. Staging via global_load_lds 16B/lane
// in 4KB chunks; row-major [row][BK] with col-block swizzle
//   phys = (log + SWZ(row)) & CBM,  SWZ(r) = r    for BK=64 (measured: 0 conflicts)
//                                   SWZ(r) = r>>1 for BK=32 (measured r9: 0 conflicts)
// XCD-aware bijective block swizzle (T1): FETCH_SIZE = ideal (measured r4).
// Counted-vmcnt pipeline (T3/T4), DEPTH buffers: vmcnt never drains to 0
// mid-loop. MEASURED r7: 2,2/BK64/D2 = 44us @ 4096x1024x4096 (from 57).
// FINAL CONFIG MAP for the K=1024 big GEMMs (f1a-class, all measured):
//   4,4/BK64/D1/256t (3 blk/CU) = 57us  <- floor of this structure
//   512t/128sq/BK64/D2 (2 blk)  = 60    (r13: lost 3rd block, FETCH 53->70)
//   4,4/BK32/D2 (3 blk)         = 65    (r9: 1-phase cover too short)
//   4,4/BK64/D2 (2 blk)         = 77    (r7: occupancy law)
//   2,2/BK64/D2 64sq tile       = 82    (r12: AI quartered, FETCH 53->166MB)
//   4,4/BK32/D3 (2 blk)         = 90    (r10: LDS ~128KB/CU effective)
// Beating 57 needs the full 8-phase 256sq schedule (m201) - out of scope.
// MODE 0: bf16 out (+bias); 1: bf16 gelu(acc+bias); 2: f32 acc+bias+res; 3: final (bf16 or f32 by flag)
template <int MODE, int MT, int NT, int BK, int MINW, int DEPTH>
__global__ __launch_bounds__(256, MINW) void gemm_kernel(const u16* __restrict__ A,
                                                         const u16* __restrict__ BT,
                                                         const void* __restrict__ bias,
                                                         const float* __restrict__ res,
                                                         void* __restrict__ Cout,
                                                         int M, int N, int K,
                                                         const int* __restrict__ flag) {
    constexpr int CB  = BK / 8;          // 16B col-blocks per row
    constexpr int CBM = CB - 1;
    constexpr int RPC = 2048 / BK;       // rows per 4KB chunk
    constexpr int NCA = (MT * 32) / RPC; // 4KB chunks in A tile
    constexpr int NCB = (NT * 32) / RPC;
    constexpr int NB  = (DEPTH > 1) ? DEPTH : 1;
    __shared__ __align__(16) u16 lsA[NB][MT * 32 * BK];
    __shared__ __align__(16) u16 lsB[NB][NT * 32 * BK];
    const int tid = threadIdx.x;
    const int lane = tid & 63;
    const int wave = tid >> 6;
    const int wm = (wave >> 1) * (MT * 16);
    const int wn = (wave & 1) * (NT * 16);

    // swizzle row-shift: see header comment
    auto swz = [](int r) { return (BK == 32) ? (r >> 1) : r; };

    // XCD-aware bijective block swizzle (nwg % 8 == 0 for all launch shapes)
    int bx = blockIdx.x, by = blockIdx.y;
    {
        int nwg = (int)(gridDim.x * gridDim.y);
        if ((nwg & 7) == 0) {
            int bid = by * gridDim.x + bx;
            int wg = (bid & 7) * (nwg >> 3) + (bid >> 3);
            bx = wg % gridDim.x;
            by = wg / gridDim.x;
        }
    }
    const int bm = by * (MT * 32);
    const int bn = bx * (NT * 32);
    const int l16 = lane & 15;
    const int lq = lane >> 4;
    const bool isf = (*flag != 0);

    floatx4 acc[MT][NT] = {};

    const int r_in = tid / CB;                            // row within chunk
    const int cb_log = ((tid & CBM) - swz(r_in)) & CBM;   // lands at phys = tid & CBM
    const int gcol = cb_log * 8;

    const u16* gA[NCA];
#pragma unroll
    for (int c = 0; c < NCA; c++) {
        int rr = bm + c * RPC + r_in; if (rr >= M) rr = M - 1;  // clamp: finite, never stored
        gA[c] = A + (size_t)rr * K + gcol;
    }
    const u16* gB[NCB];
#pragma unroll
    for (int c = 0; c < NCB; c++) {
        int rr = bn + c * RPC + r_in; if (rr >= N) rr = N - 1;
        gB[c] = BT + (size_t)rr * K + gcol;
    }

    auto stage = [&](int bf, int k0) {
#pragma unroll
        for (int c = 0; c < NCA; c++)
            __builtin_amdgcn_global_load_lds((g_void*)(gA[c] + k0),
                                             (l_void*)(&lsA[bf][c * 2048 + tid * 8]), 16, 0, 0);
#pragma unroll
        for (int c = 0; c < NCB; c++)
            __builtin_amdgcn_global_load_lds((g_void*)(gB[c] + k0),
                                             (l_void*)(&lsB[bf][c * 2048 + tid * 8]), 16, 0, 0);
    };

    auto compute = [&](int bf) {
#pragma unroll
        for (int ki = 0; ki < BK / 32; ki++) {
            short8 af[MT], bfr[NT];
#pragma unroll
            for (int mi = 0; mi < MT; mi++) {
                int ra = wm + mi * 16 + l16;
                af[mi] = *(const short8*)&lsA[bf][ra * BK + ((ki * 4 + lq + swz(ra)) & CBM) * 8];
            }
#pragma unroll
            for (int ni = 0; ni < NT; ni++) {
                int rb = wn + ni * 16 + l16;
                bfr[ni] = *(const short8*)&lsB[bf][rb * BK + ((ki * 4 + lq + swz(rb)) & CBM) * 8];
            }
#pragma unroll
            for (int mi = 0; mi < MT; mi++)
#pragma unroll
                for (int ni = 0; ni < NT; ni++)
                    acc[mi][ni] = __builtin_amdgcn_mfma_f32_16x16x32_bf16(af[mi], bfr[ni], acc[mi][ni], 0, 0, 0);
        }
    };

    if constexpr (DEPTH > 1) {
        constexpr int L = NCA + NCB;         // VMEM insts per stage per thread
        static_assert(L == 4, "counted-vmcnt literals below assume 4 loads/stage");
        const int nk = K / BK;               // nk >= DEPTH for all launch shapes
#pragma unroll
        for (int d = 0; d < DEPTH; ++d)
            stage(d, d * BK);
        int cur = 0;
        for (int t = 0; t < nk; t++) {
            const int rem = nk - 1 - t;      // tiles still in flight beyond t
            if (DEPTH >= 3 && rem >= 2)      asm volatile("s_waitcnt vmcnt(8)" ::: "memory");
            else if (rem >= 1)               asm volatile("s_waitcnt vmcnt(4)" ::: "memory");
            else                             asm volatile("s_waitcnt vmcnt(0)" ::: "memory");
            __builtin_amdgcn_s_barrier();
            compute(cur);
            __builtin_amdgcn_s_barrier();    // all waves done reading buf[cur]
            if (t + DEPTH < nk) stage(cur, (t + DEPTH) * BK);
            cur = (cur + 1 == NB) ? 0 : cur + 1;
        }
    } else {
        for (int k0 = 0; k0 < K; k0 += BK) {
            stage(0, k0);
            __syncthreads();
            compute(0);
            __syncthreads();
        }
    }

#pragma unroll
    for (int mi = 0; mi < MT; mi++) {
#pragma unroll
        for (int ni = 0; ni < NT; ni++) {
            int col = bn + wn + ni * 16 + l16;
            float bv = 0.0f;
            if (bias) bv = isf ? ((const float*)bias)[col] : b2f(((const u16*)bias)[col]);
#pragma unroll
            for (int r = 0; r < 4; r++) {
                int row = bm + wm + mi * 16 + lq * 4 + r;
                if (row < M) {
                    float v = acc[mi][ni][r] + bv;
                    size_t idx = (size_t)row * N + col;
                    if (MODE == 1) v = gelu_exact(v);
                    if (MODE == 2 || MODE == 3) v += res[idx];
                    if (MODE == 2)       ((float*)Cout)[idx] = v;
                    else if (MODE == 3) { if (isf) ((float*)Cout)[idx] = v; else ((u16*)Cout)[idx] = f2b(v); }
                    else                 ((u16*)Cout)[idx] = f2b(v);
                }
            }
        }
    }
}

// ------------------------------------------------------------ MFMA flash attention v3: 128 q-rows/block
// No online rescaling (scores bounded: |s*scale| << 80 -> exp2 overflow-safe).
// Q/K DMA-staged (swizzled stride-64); Vt XOR-swizzled; wave owns 2 strips of 16 rows.
// grid (T/128, B*16), 4 waves. cexp = scale*log2(e).
// XCD swizzle clusters the 8 q-tile blocks sharing one (b,h)'s K/V onto one XCD.
// T14 async-stage split (r11, kept): V loads for tile t+1 issued at the bottom
// of tile t; bottom barrier is counted vmcnt(2) + raw s_barrier.
__global__ __launch_bounds__(256, 2) void attn_mfma_kernel(const u16* __restrict__ q,
                                                           const u16* __restrict__ k,
                                                           const u16* __restrict__ v,
                                                           u16* __restrict__ o,
                                                           int T, int S, int ldq, int ldkv,
                                                           float cexp) {
    const int E = 1024;
    int bx = blockIdx.x, byy = blockIdx.y;
    {
        int nwg = (int)(gridDim.x * gridDim.y);
        if ((nwg & 7) == 0) {
            int bid = byy * gridDim.x + bx;
            int wg = (bid & 7) * (nwg >> 3) + (bid >> 3);
            bx = wg % gridDim.x;
            byy = wg / gridDim.x;
        }
    }
    const int b = byy >> 4, h = byy & 15;
    const int tid = threadIdx.x, wave = tid >> 6, lane = tid & 63;
    const int l16 = lane & 15, lq = lane >> 4;

    __shared__ __align__(16) u16 Qs[128 * 64];       // 16 KB
    __shared__ __align__(16) u16 Ks[64 * 64];        // 8 KB
    __shared__ __align__(16) u16 Vt[64 * 72];        // 9 KB
    __shared__ __align__(16) u16 Ps[4][16 * 72];     // 9 KB

    const int q0 = bx * 128;
    const int r8 = tid >> 3;
    const int cb_log = ((tid & 7) - r8) & 7;
    const int rv = tid >> 2, cv = (tid & 3) * 16;
    const int cbv = ((rv >> 3) ^ (tid & 3)) & 7;

    // stage Q (128 rows; T % 128 == 0)
#pragma unroll
    for (int j = 0; j < 4; j++) {
        int row = q0 + j * 32 + r8;
        __builtin_amdgcn_global_load_lds((g_void*)(q + (size_t)(b * T + row) * ldq + h * 64 + cb_log * 8),
                                         (l_void*)(Qs + j * 2048 + tid * 8), 16, 0, 0);
    }
    __syncthreads();

    short8 af[2][2];
#pragma unroll
    for (int j = 0; j < 2; j++) {
        int qr = j * 64 + wave * 16 + l16;
        af[j][0] = *(const short8*)&Qs[qr * 64 + ((lq + qr) & 7) * 8];
        af[j][1] = *(const short8*)&Qs[qr * 64 + ((lq + 4 + qr) & 7) * 8];
    }

    float lsum[2][4] = {};
    floatx4 oacc[2][4] = {};

    const int ntiles = (S + 63) >> 6;
    // prologue: V regs for tile 0
    uint4 vr0, vr1;
    {
        int sr = rv; if (sr >= S) sr = S - 1;
        const u16* vsrc = v + (size_t)(b * S + sr) * ldkv + h * 64 + cv;
        vr0 = *(const uint4*)vsrc;
        vr1 = *(const uint4*)(vsrc + 8);
    }
    for (int t = 0; t < ntiles; t++) {
        const int s0 = t * 64;
        __syncthreads();   // all waves done reading Ks/Vt of t-1
#pragma unroll
        for (int j = 0; j < 2; j++) {
            int srow = s0 + j * 32 + r8; if (srow >= S) srow = S - 1;
            __builtin_amdgcn_global_load_lds((g_void*)(k + (size_t)(b * S + srow) * ldkv + h * 64 + cb_log * 8),
                                             (l_void*)(Ks + j * 2048 + tid * 8), 16, 0, 0);
        }
        {
            // write tile t's V regs (loaded last iteration / prologue)
            const u16* vp = (const u16*)&vr0;
#pragma unroll
            for (int j = 0; j < 8; j++)
                Vt[(cv + j) * 72 + cbv * 8 + (rv & 7)] = vp[j];
            vp = (const u16*)&vr1;
#pragma unroll
            for (int j = 0; j < 8; j++)
                Vt[(cv + 8 + j) * 72 + cbv * 8 + (rv & 7)] = vp[j];
        }
        if (t + 1 < ntiles) {
            // early-issue V loads for t+1 (T14): consumed at next iteration's write
            int sr = s0 + 64 + rv; if (sr >= S) sr = S - 1;
            const u16* vsrc = v + (size_t)(b * S + sr) * ldkv + h * 64 + cv;
            vr0 = *(const uint4*)vsrc;
            vr1 = *(const uint4*)(vsrc + 8);
            // oldest 2 outstanding = this tile's K DMA -> must land; newest 2 = V prefetch, stay in flight
            asm volatile("s_waitcnt vmcnt(2) lgkmcnt(0)" ::: "memory");
        } else {
            asm volatile("s_waitcnt vmcnt(0) lgkmcnt(0)" ::: "memory");
        }
        __builtin_amdgcn_s_barrier();

        const bool tail = (s0 + 64 > S);
#pragma unroll
        for (int j = 0; j < 2; j++) {
            // scores for strip j
            floatx4 sc[4];
#pragma unroll
            for (int nt = 0; nt < 4; nt++) {
                int krow = nt * 16 + l16;
                short8 bf0 = *(const short8*)&Ks[krow * 64 + ((lq + krow) & 7) * 8];
                short8 bf1 = *(const short8*)&Ks[krow * 64 + ((lq + 4 + krow) & 7) * 8];
                floatx4 z = {};
                z = __builtin_amdgcn_mfma_f32_16x16x32_bf16(af[j][0], bf0, z, 0, 0, 0);
                z = __builtin_amdgcn_mfma_f32_16x16x32_bf16(af[j][1], bf1, z, 0, 0, 0);
                sc[nt] = z;
            }
#pragma unroll
            for (int nt = 0; nt < 4; nt++) {
                bool colv = !tail || (s0 + nt * 16 + l16 < S);
#pragma unroll
                for (int r = 0; r < 4; r++) {
                    float p = exp2f(sc[nt][r] * cexp);
                    p = colv ? p : 0.0f;
                    lsum[j][r] += p;
                    Ps[wave][(lq * 4 + r) * 72 + nt * 16 + l16] = f2b(p);
                }
            }
            short8 av0 = *(const short8*)&Ps[wave][l16 * 72 + lq * 8];
            short8 av1 = *(const short8*)&Ps[wave][l16 * 72 + 32 + lq * 8];
#pragma unroll
            for (int dt = 0; dt < 4; dt++) {
                int d = dt * 16 + l16;
                short8 bv0 = *(const short8*)&Vt[d * 72 + ((lq ^ dt) & 7) * 8];
                short8 bv1 = *(const short8*)&Vt[d * 72 + (((4 + lq) ^ dt) & 7) * 8];
                oacc[j][dt] = __builtin_amdgcn_mfma_f32_16x16x32_bf16(av0, bv0, oacc[j][dt], 0, 0, 0);
                oacc[j][dt] = __builtin_amdgcn_mfma_f32_16x16x32_bf16(av1, bv1, oacc[j][dt], 0, 0, 0);
            }
        }
    }

#pragma unroll
    for (int j = 0; j < 2; j++)
#pragma unroll
        for (int r = 0; r < 4; r++) {
#pragma unroll
            for (int off = 1; off < 16; off <<= 1)
                lsum[j][r] += __shfl_xor(lsum[j][r], off, 64);
        }

#pragma unroll
    for (int j = 0; j < 2; j++)
#pragma unroll
        for (int r = 0; r < 4; r++) {
            float inv = 1.0f / lsum[j][r];
            int row = q0 + j * 64 + wave * 16 + lq * 4 + r;
            u16* dst = o + (size_t)(b * T + row) * E + h * 64 + l16;
#pragma unroll
            for (int dt = 0; dt < 4; dt++)
                dst[dt * 16] = f2b(oacc[j][dt][r] * inv);
        }
}

// ------------------------------------------------------------ host
extern "C" void kernel_launch(void* const* d_in, const int* in_sizes, int n_in,
                              void* d_out, int out_size, void* d_ws, size_t ws_size,
                              hipStream_t stream) {
    const void* x_in = d_in[0];
    const void* ctx  = d_in[1];
    const void* sq_w = d_in[2];
    const void* sk_w = d_in[3];
    const void* sv_w = d_in[4];
    const void* so_w = d_in[5];
    const void* so_b = d_in[6];
    const void* cq_w = d_in[7];
    const void* ck_w = d_in[8];
    const void* cv_w = d_in[9];
    const void* co_w = d_in[10];
    const void* co_b = d_in[11];
    const void* n1_g = d_in[12];
    const void* n1_b = d_in[13];
    const void* n2_g = d_in[14];
    const void* n2_b = d_in[15];
    const void* n3_g = d_in[16];
    const void* n3_b = d_in[17];
    const void* n4_g = d_in[18];
    const void* n4_b = d_in[19];
    const void* f1_w1 = d_in[20];
    const void* f1_b1 = d_in[21];
    const void* f1_w2 = d_in[22];
    const void* f1_b2 = d_in[23];
    const void* f2_w1 = d_in[24];
    const void* f2_b1 = d_in[25];
    const void* f2_w2 = d_in[26];
    const void* f2_b2 = d_in[27];

    const int B = 4, T = 1024, H = 1024, FF = 4096, CD = 768, S = 77;
    const int BT_ = B * T;   // 4096
    const int BS_ = B * S;   // 308

    char* ws = (char*)d_ws;
    size_t off = 0;
    auto alloc = [&](size_t bytes) { char* p = ws + off; off += (bytes + 255) & ~(size_t)255; return p; };
    int*   flag = (int*)alloc(256);
    u16*   ctxb = (u16*)alloc((size_t)BS_ * CD * 2);
    float* xcur = (float*)alloc((size_t)BT_ * H * 4);
    const size_t MEL = 1024 * 1024;
    u16* wqkv = (u16*)alloc(3 * MEL * 2);
    u16* wso  = (u16*)alloc(MEL * 2);
    u16* wcq  = (u16*)alloc(MEL * 2);
    u16* wckv = (u16*)alloc((size_t)2 * H * CD * 2);
    u16* wco  = (u16*)alloc(MEL * 2);
    u16* wf1a = (u16*)alloc((size_t)H * FF * 2);
    u16* wf1b = (u16*)alloc((size_t)H * FF * 2);
    u16* wf2a = (u16*)alloc((size_t)H * FF * 2);
    u16* wf2b = (u16*)alloc((size_t)H * FF * 2);
    u16* U    = (u16*)alloc((size_t)40 * 1024 * 1024);
    (void)ws_size; (void)n_in; (void)in_sizes; (void)out_size;

    const size_t AEL = (size_t)BT_ * H;
    u16* lnb  = U;
    u16* qkvb = U + AEL;
    u16* ob   = U + 4 * AEL;
    u16* hb   = U + AEL;
    u16* qb   = U + AEL;
    u16* kvb  = U + 2 * AEL;

    TPack tp;
    auto ent = [&](int i, const void* src, u16* dst, int R, int C) {
        tp.e[i] = TEnt{ src, dst, R, C, C / 64, (C / 64) * (R / 64) };
    };
    ent(0,  sq_w, wqkv,           H,  H);
    ent(1,  sk_w, wqkv + MEL,     H,  H);
    ent(2,  sv_w, wqkv + 2 * MEL, H,  H);
    ent(3,  so_w, wso,            H,  H);
    ent(4,  cq_w, wcq,            H,  H);
    ent(5,  ck_w, wckv,           CD, H);
    ent(6,  cv_w, wckv + (size_t)H * CD, CD, H);
    ent(7,  co_w, wco,            H,  H);
    ent(8,  f1_w1, wf1a,          H,  FF);
    ent(9,  f1_w2, wf1b,          FF, H);
    ent(10, f2_w1, wf2a,          H,  FF);
    ent(11, f2_w2, wf2b,          FF, H);

    const dim3 g_qkv(3072 / 128, BT_ / 128);
    const dim3 g_ff(FF / 128, BT_ / 128);
    const dim3 g_n1024(H / 64, BT_ / 64);            // 1024 blocks, 64x64 tiles, 4 blk/CU
    const dim3 g_ckv(2048 / 64, (BS_ + 63) / 64);
    const dim3 attn_grid(T / 128, B * 16);
    const float cexp = 0.125f * 1.4426950408889634f;

    sniff_kernel<<<1, 64, 0, stream>>>((const u16*)x_in, flag);
    cvt_bf_kernel<<<(BS_ * CD / 4 + 255) / 256, 256, 0, stream>>>(ctx, ctxb, BS_ * CD / 4, flag);
    transpose_batch_kernel<<<dim3(1024, 12), 256, 0, stream>>>(tp, flag);

    // ---- self-attention block
    ln_kernel<<<BT_, 256, 0, stream>>>(x_in, xcur, n1_g, n1_b, lnb, flag, 1);
    gemm_kernel<0, 4, 4, 64, 3, 1><<<g_qkv, 256, 0, stream>>>(lnb, wqkv, nullptr, nullptr, qkvb, BT_, 3072, H, flag);
    attn_mfma_kernel<<<attn_grid, 256, 0, stream>>>(qkvb, qkvb + 1024, qkvb + 2048, ob, T, T, 3072, 3072, cexp);
    gemm_kernel<2, 2, 2, 64, 4, 2><<<g_n1024, 256, 0, stream>>>(ob, wso, so_b, xcur, xcur, BT_, H, H, flag);

    // ---- FFN 1
    ln_kernel<<<BT_, 256, 0, stream>>>(xcur, nullptr, n2_g, n2_b, lnb, flag, 0);
    gemm_kernel<1, 4, 4, 64, 3, 1><<<g_ff, 256, 0, stream>>>(lnb, wf1a, f1_b1, nullptr, hb, BT_, FF, H, flag);
    gemm_kernel<2, 2, 2, 64, 4, 2><<<g_n1024, 256, 0, stream>>>(hb, wf1b, f1_b2, xcur, xcur, BT_, H, FF, flag);

    // ---- cross-attention block
    ln_kernel<<<BT_, 256, 0, stream>>>(xcur, nullptr, n3_g, n3_b, lnb, flag, 0);
    gemm_kernel<0, 2, 2, 64, 4, 2><<<g_n1024, 256, 0, stream>>>(lnb, wcq, nullptr, nullptr, qb, BT_, H, H, flag);
    gemm_kernel<0, 2, 2, 64, 4, 2><<<g_ckv, 256, 0, stream>>>(ctxb, wckv, nullptr, nullptr, kvb, BS_, 2048, CD, flag);
    attn_mfma_kernel<<<attn_grid, 256, 0, stream>>>(qb, kvb, kvb + 1024, ob, T, S, 1024, 2048, cexp);
    gemm_kernel<2, 2, 2, 64, 4, 2><<<g_n1024, 256, 0, stream>>>(ob, wco, co_b, xcur, xcur, BT_, H, H, flag);

    // ---- FFN 2 (final output -> d_out)
    ln_kernel<<<BT_, 256, 0, stream>>>(xcur, nullptr, n4_g, n4_b, lnb, flag, 0);
    gemm_kernel<1, 4, 4, 64, 3, 1><<<g_ff, 256, 0, stream>>>(lnb, wf2a, f2_b1, nullptr, hb, BT_, FF, H, flag);
    gemm_kernel<3, 2, 2, 64, 4, 2><<<g_n1024, 256, 0, stream>>>(hb, wf2b, f2_b2, xcur, d_out, BT_, H, FF, flag);
}